// Round 13
// baseline (99.684 us; speedup 1.0000x reference)
//
#include <hip/hip_runtime.h>
#include <hip/hip_bf16.h>

#define DIM 768
#define NH  12
#define HW  64
#define BB  32
#define NV  100
#define NQ  32
#define NA  32

#define VP_ELEMS (BB * NV * DIM)   // 2457600
#define QP_ELEMS (BB * NQ * DIM)   // 786432
#define AP_ELEMS (BB * NA * DIM)   // 786432
#define S1 (VP_ELEMS)
#define S2 (S1 + QP_ELEMS)
#define WELEMS (DIM * DIM)         // 589824
#define NBH (BB * NH)              // 384

typedef __attribute__((ext_vector_type(8))) short     bf16x8;
typedef __attribute__((ext_vector_type(8))) unsigned short u16x8;
typedef __attribute__((ext_vector_type(4))) float     f32x4;

__device__ __forceinline__ float bf16r(float x) {
    return __bfloat162float(__float2bfloat16(x));
}
__device__ __forceinline__ unsigned short f2bu(float x) {
    __hip_bfloat16 h = __float2bfloat16(x);
    return *reinterpret_cast<unsigned short*>(&h);
}
__device__ __forceinline__ float bu2f(unsigned short u) {
    union { unsigned int i; float f; } c;
    c.i = ((unsigned int)u) << 16;
    return c.f;
}

// ---------------------------------------------------------------------------
// Convert 6 weights (f32, [k][n]) -> bf16 TRANSPOSED [n][k], via 64x64 LDS
// tiles. Coalesced read + coalesced write.
// ---------------------------------------------------------------------------
__global__ __launch_bounds__(256) void conv_wT(
    const float* __restrict__ W0, const float* __restrict__ W1,
    const float* __restrict__ W2, const float* __restrict__ W3,
    const float* __restrict__ W4, const float* __restrict__ W5,
    unsigned short* __restrict__ WtAll)
{
    const int widx = blockIdx.x / 144;
    const int t    = blockIdx.x % 144;
    const int tr = t / 12, tc = t % 12;
    const float* W = (widx == 0) ? W0 : (widx == 1) ? W1 : (widx == 2) ? W2
                   : (widx == 3) ? W3 : (widx == 4) ? W4 : W5;
    unsigned short* Wt = WtAll + (size_t)widx * WELEMS;

    __shared__ float tile[64][65];
    const int c = threadIdx.x & 63, r4 = threadIdx.x >> 6;
#pragma unroll
    for (int it = 0; it < 16; ++it) {
        int r = it * 4 + r4;
        tile[r][c] = W[(size_t)(tr * 64 + r) * DIM + tc * 64 + c];
    }
    __syncthreads();
#pragma unroll
    for (int it = 0; it < 16; ++it) {
        int r = it * 4 + r4;
        Wt[(size_t)(tc * 64 + r) * DIM + tr * 64 + c] = f2bu(tile[c][r]);
    }
}

// ---------------------------------------------------------------------------
// MFMA GEMM over 3 pointer-sets. Y = X @ W + bias.  (round-8 validated
// 128x128 structure: 2x2 waves, 4x4 frags/wave, BK=32 — halves per-output
// LDS traffic vs the 64x128 N-split variant.)
// OUT=0: X is f32 (converted during A-staging), writes bf16 Y.
// OUT=1: X is bf16, writes f32 out scaled by marginal, bf16-rounded.
// Tiles: set0 25x6=[0,150), set1 8x6=[150,198), set2 8x6=[198,246).
// ---------------------------------------------------------------------------
template <int OUT>
__global__ __launch_bounds__(256) void gemm_mfma(
    const void* __restrict__ X0v, const void* __restrict__ X1v, const void* __restrict__ X2v,
    const unsigned short* __restrict__ W0, const unsigned short* __restrict__ W1,
    const unsigned short* __restrict__ W2,
    const float* __restrict__ c0, const float* __restrict__ c1, const float* __restrict__ c2,
    unsigned short* __restrict__ Y0, unsigned short* __restrict__ Y1,
    unsigned short* __restrict__ Y2,
    float* __restrict__ O0, float* __restrict__ O1, float* __restrict__ O2,
    const float* __restrict__ m0, const float* __restrict__ m1, const float* __restrict__ m2)
{
    __shared__ unsigned short As[128 * 32];
    __shared__ unsigned short Bs[128 * 32];

    const int t = blockIdx.x;
    int set, loc;
    if (t < 150)      { set = 0; loc = t; }
    else if (t < 198) { set = 1; loc = t - 150; }
    else              { set = 2; loc = t - 198; }
    const int tm = loc / 6, tn = loc % 6;

    const void* Xv           = (set == 0) ? X0v : (set == 1) ? X1v : X2v;
    const unsigned short* Wt = (set == 0) ? W0 : (set == 1) ? W1 : W2;
    const float* bias        = (set == 0) ? c0 : (set == 1) ? c1 : c2;
    unsigned short* Y        = (set == 0) ? Y0 : (set == 1) ? Y1 : Y2;
    float* Out               = (set == 0) ? O0 : (set == 1) ? O1 : O2;
    const float* mg          = (set == 0) ? m0 : (set == 1) ? m1 : m2;
    const int S              = (set == 0) ? NV : NQ;

    const int tid  = threadIdx.x;
    const int lane = tid & 63;
    const int wave = tid >> 6;
    const int wr = wave >> 1, wc = wave & 1;
    const int bm = tm * 128, bn = tn * 128;

    const int srow0 = tid >> 2, skc = (tid & 3) << 3;

    f32x4 acc[4][4] = {};

    for (int k0 = 0; k0 < DIM; k0 += 32) {
        if (OUT == 0) {
            const float* Xf = (const float*)Xv;
#pragma unroll
            for (int hh = 0; hh < 2; ++hh) {
                const int r = srow0 + hh * 64;
                const float4 f0 = *(const float4*)&Xf[(size_t)(bm + r) * DIM + k0 + skc];
                const float4 f1 = *(const float4*)&Xf[(size_t)(bm + r) * DIM + k0 + skc + 4];
                u16x8 u;
                u[0] = f2bu(f0.x); u[1] = f2bu(f0.y); u[2] = f2bu(f0.z); u[3] = f2bu(f0.w);
                u[4] = f2bu(f1.x); u[5] = f2bu(f1.y); u[6] = f2bu(f1.z); u[7] = f2bu(f1.w);
                *(u16x8*)&As[r * 32 + skc] = u;
            }
        } else {
            const unsigned short* Xb = (const unsigned short*)Xv;
            *(u16x8*)&As[srow0 * 32 + skc] =
                *(const u16x8*)&Xb[(size_t)(bm + srow0) * DIM + k0 + skc];
            *(u16x8*)&As[(srow0 + 64) * 32 + skc] =
                *(const u16x8*)&Xb[(size_t)(bm + srow0 + 64) * DIM + k0 + skc];
        }
        *(u16x8*)&Bs[srow0 * 32 + skc] =
            *(const u16x8*)&Wt[(size_t)(bn + srow0) * DIM + k0 + skc];
        *(u16x8*)&Bs[(srow0 + 64) * 32 + skc] =
            *(const u16x8*)&Wt[(size_t)(bn + srow0 + 64) * DIM + k0 + skc];
        __syncthreads();

        bf16x8 af[4], bfr[4];
#pragma unroll
        for (int mi = 0; mi < 4; ++mi)
            af[mi] = *(const bf16x8*)&As[(wr * 64 + mi * 16 + (lane & 15)) * 32 + (lane >> 4) * 8];
#pragma unroll
        for (int ni = 0; ni < 4; ++ni)
            bfr[ni] = *(const bf16x8*)&Bs[(wc * 64 + ni * 16 + (lane & 15)) * 32 + (lane >> 4) * 8];
#pragma unroll
        for (int mi = 0; mi < 4; ++mi)
#pragma unroll
            for (int ni = 0; ni < 4; ++ni)
                acc[mi][ni] = __builtin_amdgcn_mfma_f32_16x16x32_bf16(
                    af[mi], bfr[ni], acc[mi][ni], 0, 0, 0);
        __syncthreads();
    }

    // C layout (validated): n-col = lane&15, m-row = (lane>>4)*4 + r
    const int h = (bn + wc * 64) >> 6;   // uniform per wave (64-col span)
#pragma unroll
    for (int mi = 0; mi < 4; ++mi) {
#pragma unroll
        for (int r = 0; r < 4; ++r) {
            const int m = bm + wr * 64 + mi * 16 + (lane >> 4) * 4 + r;
            float mgv = 0.f;
            if (OUT) {
                const int bb = m / S, ss = m - bb * S;
                mgv = mg[(bb * NH + h) * S + ss];
            }
#pragma unroll
            for (int ni = 0; ni < 4; ++ni) {
                const int n = bn + wc * 64 + ni * 16 + (lane & 15);
                const float val = acc[mi][ni][r] + bias[n];
                if (!OUT) Y[(size_t)m * DIM + n] = f2bu(val);
                else      Out[(size_t)m * DIM + n] = bf16r(val * mgv);
            }
        }
    }
}

// ---------------------------------------------------------------------------
// MFMA marginal kernel v3c. Grid = NBH*4 (pair-quarters), 256 thr = 4 waves,
// wave owns 4 pair-tiles. q/a head slices kept in LDS as bf16 (half the
// read bytes of v3b; conversion on read is bit-identical). Per-tile sum ts
// feeds za/zq once per tile instead of per-element.
// ---------------------------------------------------------------------------
__global__ __launch_bounds__(256, 2) void attn_marginals_mfma(
    const unsigned short* __restrict__ vp, const unsigned short* __restrict__ qp,
    const unsigned short* __restrict__ ap,
    const int* __restrict__ vmask, const int* __restrict__ qmask, const int* __restrict__ amask,
    float* __restrict__ pv_part, float* __restrict__ pa_part, float* __restrict__ pq_raw)
{
    const int bh = blockIdx.x >> 2, qr = blockIdx.x & 3;
    const int b = bh / NH, h = bh % NH;
    const int tid = threadIdx.x, lane = tid & 63, wave = tid >> 6;
    const int col = lane & 15, rg = lane >> 4;

    __shared__ unsigned short vhs[112 * 72];   // bf16
    __shared__ unsigned short qhs[NQ * 72];    // bf16
    __shared__ unsigned short ahs[NA * 72];    // bf16
    __shared__ float vm_mul[112], qm_mul[NQ], am_mul[NA];
    __shared__ float pv_sh[112], pa_sh[NA];

    for (int i = tid; i < 112 * 8; i += 256) {
        int v = i >> 3, c = i & 7;
        u16x8 val = {};
        if (v < NV) val = *(const u16x8*)&vp[(size_t)(b * NV + v) * DIM + h * 64 + c * 8];
        *(u16x8*)&vhs[v * 72 + c * 8] = val;
    }
    {   // 256 threads, exactly one u16x8 each for q and a
        const int s = tid >> 3, c = tid & 7;
        *(u16x8*)&qhs[s * 72 + c * 8] =
            *(const u16x8*)&qp[(size_t)(b * NQ + s) * DIM + h * 64 + c * 8];
        *(u16x8*)&ahs[s * 72 + c * 8] =
            *(const u16x8*)&ap[(size_t)(b * NA + s) * DIM + h * 64 + c * 8];
    }
    if (tid < 112) { vm_mul[tid] = (tid < NV && vmask[b * NV + tid] == 0) ? 1.f : 0.f; pv_sh[tid] = 0.f; }
    if (tid < NQ)  { qm_mul[tid] = qmask[b * NQ + tid] ? 0.f : 1.f; }
    if (tid < NA)  { am_mul[tid] = amask[b * NA + tid] ? 0.f : 1.f; pa_sh[tid] = 0.f; }
    __syncthreads();

    const int qbase = qr * 8 + wave * 2;
    float pvacc[7][4] = {};
    float za0 = 0.f, za1 = 0.f;
    float zq0 = 0.f, zq1 = 0.f;
    const float sc2 = 0.125f * 1.44269504088896f;   // scale * log2(e)

#pragma unroll
    for (int t = 0; t < 4; ++t) {
        const int qi = qbase + (t >> 1);
        const int ai = ((t & 1) << 4) + col;
        const u16x8 qv0 = *(const u16x8*)&qhs[qi * 72 + rg * 8];
        const u16x8 qv1 = *(const u16x8*)&qhs[qi * 72 + 32 + rg * 8];
        const u16x8 av0 = *(const u16x8*)&ahs[ai * 72 + rg * 8];
        const u16x8 av1 = *(const u16x8*)&ahs[ai * 72 + 32 + rg * 8];
        bf16x8 bf0, bf1;
#pragma unroll
        for (int j = 0; j < 8; ++j) {
            bf0[j] = (short)f2bu(bu2f(qv0[j]) * bu2f(av0[j]));
            bf1[j] = (short)f2bu(bu2f(qv1[j]) * bu2f(av1[j]));
        }
        const float pmul = qm_mul[qi] * am_mul[ai];
        float ts = 0.f;
#pragma unroll
        for (int vt = 0; vt < 7; ++vt) {
            const bf16x8 a0 = *(const bf16x8*)&vhs[(vt * 16 + col) * 72 + rg * 8];
            const bf16x8 a1 = *(const bf16x8*)&vhs[(vt * 16 + col) * 72 + 32 + rg * 8];
            f32x4 acc = {};
            acc = __builtin_amdgcn_mfma_f32_16x16x32_bf16(a0, bf0, acc, 0, 0, 0);
            acc = __builtin_amdgcn_mfma_f32_16x16x32_bf16(a1, bf1, acc, 0, 0, 0);
#pragma unroll
            for (int r = 0; r < 4; ++r) {
                const float e = exp2f(acc[r] * sc2) * vm_mul[vt * 16 + rg * 4 + r] * pmul;
                pvacc[vt][r] += e;
                ts += e;
            }
        }
        if (t & 1) za1 += ts; else za0 += ts;
        if (t & 2) zq1 += ts; else zq0 += ts;
    }

    // end-of-kernel reductions
#pragma unroll
    for (int vt = 0; vt < 7; ++vt) {
#pragma unroll
        for (int r = 0; r < 4; ++r) {
            float x = pvacc[vt][r];
            x += __shfl_xor(x, 1); x += __shfl_xor(x, 2);
            x += __shfl_xor(x, 4); x += __shfl_xor(x, 8);
            if (col == 0) atomicAdd(&pv_sh[vt * 16 + rg * 4 + r], x);
        }
    }
    {
        float x = za0;
        x += __shfl_xor(x, 16); x += __shfl_xor(x, 32);
        if (rg == 0) atomicAdd(&pa_sh[col], x);
        float y = za1;
        y += __shfl_xor(y, 16); y += __shfl_xor(y, 32);
        if (rg == 0) atomicAdd(&pa_sh[16 + col], y);
    }
    {
        float x = zq0;
        x += __shfl_xor(x, 1); x += __shfl_xor(x, 2); x += __shfl_xor(x, 4);
        x += __shfl_xor(x, 8); x += __shfl_xor(x, 16); x += __shfl_xor(x, 32);
        if (lane == 0) pq_raw[bh * NQ + qbase] = x;
        float y = zq1;
        y += __shfl_xor(y, 1); y += __shfl_xor(y, 2); y += __shfl_xor(y, 4);
        y += __shfl_xor(y, 8); y += __shfl_xor(y, 16); y += __shfl_xor(y, 32);
        if (lane == 0) pq_raw[bh * NQ + qbase + 1] = y;
    }
    __syncthreads();
    if (tid < 112) pv_part[(size_t)(bh * 4 + qr) * 112 + tid] = pv_sh[tid];
    if (tid < NA)  pa_part[(size_t)(bh * 4 + qr) * NA + tid] = pa_sh[tid];
}

// ---------------------------------------------------------------------------
// Normalize: Z = sum(pq_raw), combine 4 quarters, scale by 1/Z.
// ---------------------------------------------------------------------------
__global__ __launch_bounds__(128) void normalize_marg(
    const float* __restrict__ pv_part, const float* __restrict__ pa_part,
    float* __restrict__ pq, float* __restrict__ pv, float* __restrict__ pa)
{
    const int bh = blockIdx.x;
    const int tid = threadIdx.x, lane = tid & 63;
    __shared__ float zsh;
    if (tid < 64) {
        float x = (lane < NQ) ? pq[bh * NQ + lane] : 0.f;
        x += __shfl_xor(x, 1); x += __shfl_xor(x, 2); x += __shfl_xor(x, 4);
        x += __shfl_xor(x, 8); x += __shfl_xor(x, 16); x += __shfl_xor(x, 32);
        if (lane == 0) zsh = x;
    }
    __syncthreads();
    const float invZ = 1.0f / zsh;
    if (tid < NV) {
        float s = 0.f;
#pragma unroll
        for (int p = 0; p < 4; ++p)
            s += pv_part[(size_t)(bh * 4 + p) * 112 + tid];
        pv[bh * NV + tid] = s * invZ;
    }
    if (tid < NQ) pq[bh * NQ + tid] *= invZ;
    if (tid < NA) {
        float s = 0.f;
#pragma unroll
        for (int p = 0; p < 4; ++p)
            s += pa_part[(size_t)(bh * 4 + p) * NA + tid];
        pa[bh * NA + tid] = s * invZ;
    }
}

// ---------------------------------------------------------------------------
extern "C" void kernel_launch(void* const* d_in, const int* in_sizes, int n_in,
                              void* d_out, int out_size, void* d_ws, size_t ws_size,
                              hipStream_t stream)
{
    const float* v     = (const float*)d_in[0];
    const float* q     = (const float*)d_in[1];
    const float* a     = (const float*)d_in[2];
    const int*   vmask = (const int*)d_in[3];
    const int*   qmask = (const int*)d_in[4];
    const int*   amask = (const int*)d_in[5];
    const float* Wv  = (const float*)d_in[6];
    const float* bv  = (const float*)d_in[7];
    const float* Wq  = (const float*)d_in[8];
    const float* bq  = (const float*)d_in[9];
    const float* Wa  = (const float*)d_in[10];
    const float* ba  = (const float*)d_in[11];
    const float* Wvo = (const float*)d_in[12];
    const float* bvo = (const float*)d_in[13];
    const float* Wqo = (const float*)d_in[14];
    const float* bqo = (const float*)d_in[15];
    const float* Wao = (const float*)d_in[16];
    const float* bao = (const float*)d_in[17];
    float* out = (float*)d_out;          // reference output dtype is FLOAT32

    unsigned short* wsu = (unsigned short*)d_ws;
    unsigned short* WtAll = wsu;                    // 6 * 589824
    unsigned short* vpb   = WtAll + 6 * WELEMS;     // 2457600
    unsigned short* qpb   = vpb + VP_ELEMS;         // 786432
    unsigned short* apb   = qpb + QP_ELEMS;         // 786432
    float* fbase   = (float*)(apb + AP_ELEMS);
    float* pv_part = fbase;                         // 384*4*112 = 172032
    float* pa_part = pv_part + NBH * 4 * 112;       // 384*4*32  = 49152
    float* pq      = pa_part + NBH * 4 * NA;        // 384*32    = 12288
    float* pv      = pq + NBH * NQ;                 // 384*100   = 38400
    float* pa      = pv + NBH * NV;                 // 384*32    = 12288
    // ws total ~15.4 MB

    conv_wT<<<dim3(6 * 144), dim3(256), 0, stream>>>(Wv, Wq, Wa, Wvo, Wqo, Wao, WtAll);

    gemm_mfma<0><<<dim3(246), dim3(256), 0, stream>>>(
        v, q, a,
        WtAll + 0 * WELEMS, WtAll + 1 * WELEMS, WtAll + 2 * WELEMS,
        bv, bq, ba,
        vpb, qpb, apb,
        nullptr, nullptr, nullptr,
        nullptr, nullptr, nullptr);

    attn_marginals_mfma<<<dim3(NBH * 4), dim3(256), 0, stream>>>(
        vpb, qpb, apb, vmask, qmask, amask, pv_part, pa_part, pq);

    normalize_marg<<<dim3(NBH), dim3(128), 0, stream>>>(pv_part, pa_part, pq, pv, pa);

    gemm_mfma<1><<<dim3(246), dim3(256), 0, stream>>>(
        vpb, qpb, apb,
        WtAll + 3 * WELEMS, WtAll + 4 * WELEMS, WtAll + 5 * WELEMS,
        bvo, bqo, bao,
        nullptr, nullptr, nullptr,
        out, out + S1, out + S2,
        pv, pq, pa);
}

// Round 14
// 88.607 us; speedup vs baseline: 1.1250x; 1.1250x over previous
//
#include <hip/hip_runtime.h>
#include <hip/hip_bf16.h>

#define DIM 768
#define NH  12
#define HW  64
#define BB  32
#define NV  100
#define NQ  32
#define NA  32

#define VP_ELEMS (BB * NV * DIM)   // 2457600
#define QP_ELEMS (BB * NQ * DIM)   // 786432
#define AP_ELEMS (BB * NA * DIM)   // 786432
#define S1 (VP_ELEMS)
#define S2 (S1 + QP_ELEMS)
#define WELEMS (DIM * DIM)         // 589824
#define NBH (BB * NH)              // 384

typedef __attribute__((ext_vector_type(8))) short     bf16x8;
typedef __attribute__((ext_vector_type(8))) unsigned short u16x8;
typedef __attribute__((ext_vector_type(4))) float     f32x4;

__device__ __forceinline__ float bf16r(float x) {
    return __bfloat162float(__float2bfloat16(x));
}
__device__ __forceinline__ unsigned short f2bu(float x) {
    __hip_bfloat16 h = __float2bfloat16(x);
    return *reinterpret_cast<unsigned short*>(&h);
}
__device__ __forceinline__ float bu2f(unsigned short u) {
    union { unsigned int i; float f; } c;
    c.i = ((unsigned int)u) << 16;
    return c.f;
}

// ---------------------------------------------------------------------------
// Deterministic mask compaction, one block of 128 per b.
// Ballot-prefix keeps ascending order (deterministic summation order).
// ---------------------------------------------------------------------------
__global__ __launch_bounds__(128) void compact_masks(
    const int* __restrict__ vmask, const int* __restrict__ qmask,
    int* __restrict__ vidx_g, int* __restrict__ qidx_g, int* __restrict__ cnts_g)
{
    const int b = blockIdx.x;
    const int tid = threadIdx.x, lane = tid & 63, w = tid >> 6;
    __shared__ int c0;

    const bool mv = (tid < NV) && (vmask[b * NV + tid] == 0);
    const unsigned long long bal = __ballot(mv);
    const int pre = __popcll(bal & ((1ull << lane) - 1ull));
    if (w == 0 && lane == 0) c0 = __popcll(bal);
    __syncthreads();
    const int base = (w == 0) ? 0 : c0;
    if (mv) vidx_g[b * NV + base + pre] = tid;
    if (tid == 64) cnts_g[b * 2 + 0] = c0 + __popcll(bal);
    if (tid == 64 && false) {}

    if (w == 0) {
        const bool mq = (lane < NQ) && (qmask[b * NQ + lane] == 0);
        const unsigned long long balq = __ballot(mq);
        const int preq = __popcll(balq & ((1ull << lane) - 1ull));
        if (mq) qidx_g[b * NQ + preq] = lane;
        if (lane == 0) cnts_g[b * 2 + 1] = __popcll(balq);
    }
}

// ---------------------------------------------------------------------------
// Convert 6 weights (f32, [k][n]) -> bf16 TRANSPOSED [n][k], via 64x64 LDS
// tiles. Coalesced read + coalesced write.
// ---------------------------------------------------------------------------
__global__ __launch_bounds__(256) void conv_wT(
    const float* __restrict__ W0, const float* __restrict__ W1,
    const float* __restrict__ W2, const float* __restrict__ W3,
    const float* __restrict__ W4, const float* __restrict__ W5,
    unsigned short* __restrict__ WtAll)
{
    const int widx = blockIdx.x / 144;
    const int t    = blockIdx.x % 144;
    const int tr = t / 12, tc = t % 12;
    const float* W = (widx == 0) ? W0 : (widx == 1) ? W1 : (widx == 2) ? W2
                   : (widx == 3) ? W3 : (widx == 4) ? W4 : W5;
    unsigned short* Wt = WtAll + (size_t)widx * WELEMS;

    __shared__ float tile[64][65];
    const int c = threadIdx.x & 63, r4 = threadIdx.x >> 6;
#pragma unroll
    for (int it = 0; it < 16; ++it) {
        int r = it * 4 + r4;
        tile[r][c] = W[(size_t)(tr * 64 + r) * DIM + tc * 64 + c];
    }
    __syncthreads();
#pragma unroll
    for (int it = 0; it < 16; ++it) {
        int r = it * 4 + r4;
        Wt[(size_t)(tc * 64 + r) * DIM + tr * 64 + c] = f2bu(tile[c][r]);
    }
}

// ---------------------------------------------------------------------------
// MFMA GEMM over 3 pointer-sets (round-12 validated 64x128 variant).
// 64x128 tile (MxN), 256 thr = 4 waves; each wave 64x32 (4x2 frags), BK=32.
// OUT=0: X is f32 (converted in A-staging), writes bf16 Y.
// OUT=1: X is bf16, writes f32 out scaled by marginal, bf16-rounded.
// Tiles: set0 50x6=[0,300), set1 16x6=[300,396), set2 16x6=[396,492).
// ---------------------------------------------------------------------------
template <int OUT>
__global__ __launch_bounds__(256) void gemm_mfma(
    const void* __restrict__ X0v, const void* __restrict__ X1v, const void* __restrict__ X2v,
    const unsigned short* __restrict__ W0, const unsigned short* __restrict__ W1,
    const unsigned short* __restrict__ W2,
    const float* __restrict__ c0, const float* __restrict__ c1, const float* __restrict__ c2,
    unsigned short* __restrict__ Y0, unsigned short* __restrict__ Y1,
    unsigned short* __restrict__ Y2,
    float* __restrict__ O0, float* __restrict__ O1, float* __restrict__ O2,
    const float* __restrict__ m0, const float* __restrict__ m1, const float* __restrict__ m2)
{
    __shared__ unsigned short As[64 * 32];
    __shared__ unsigned short Bs[128 * 32];

    const int t = blockIdx.x;
    int set, loc;
    if (t < 300)      { set = 0; loc = t; }
    else if (t < 396) { set = 1; loc = t - 300; }
    else              { set = 2; loc = t - 396; }
    const int tm = loc / 6, tn = loc % 6;

    const void* Xv           = (set == 0) ? X0v : (set == 1) ? X1v : X2v;
    const unsigned short* Wt = (set == 0) ? W0 : (set == 1) ? W1 : W2;
    const float* bias        = (set == 0) ? c0 : (set == 1) ? c1 : c2;
    unsigned short* Y        = (set == 0) ? Y0 : (set == 1) ? Y1 : Y2;
    float* Out               = (set == 0) ? O0 : (set == 1) ? O1 : O2;
    const float* mg          = (set == 0) ? m0 : (set == 1) ? m1 : m2;
    const int S              = (set == 0) ? NV : NQ;

    const int tid = threadIdx.x, lane = tid & 63, wave = tid >> 6;
    const int col = lane & 15, rg = lane >> 4;
    const int bm = tm * 64, bn = tn * 128;

    const int arow = tid >> 2, akc = (tid & 3) << 3;   // A: 8 bf16 / thread
    const int brow = tid >> 1, bkc = (tid & 1) << 4;   // B: 16 bf16 / thread

    f32x4 acc[4][2] = {};

    for (int k0 = 0; k0 < DIM; k0 += 32) {
        if (OUT == 0) {
            const float* Xf = (const float*)Xv;
            const float4 f0 = *(const float4*)&Xf[(size_t)(bm + arow) * DIM + k0 + akc];
            const float4 f1 = *(const float4*)&Xf[(size_t)(bm + arow) * DIM + k0 + akc + 4];
            u16x8 u;
            u[0] = f2bu(f0.x); u[1] = f2bu(f0.y); u[2] = f2bu(f0.z); u[3] = f2bu(f0.w);
            u[4] = f2bu(f1.x); u[5] = f2bu(f1.y); u[6] = f2bu(f1.z); u[7] = f2bu(f1.w);
            *(u16x8*)&As[arow * 32 + akc] = u;
        } else {
            const unsigned short* Xb = (const unsigned short*)Xv;
            *(u16x8*)&As[arow * 32 + akc] =
                *(const u16x8*)&Xb[(size_t)(bm + arow) * DIM + k0 + akc];
        }
        *(u16x8*)&Bs[brow * 32 + bkc] =
            *(const u16x8*)&Wt[(size_t)(bn + brow) * DIM + k0 + bkc];
        *(u16x8*)&Bs[brow * 32 + bkc + 8] =
            *(const u16x8*)&Wt[(size_t)(bn + brow) * DIM + k0 + bkc + 8];
        __syncthreads();

        bf16x8 af[4], bfr[2];
#pragma unroll
        for (int mi = 0; mi < 4; ++mi)
            af[mi] = *(const bf16x8*)&As[(mi * 16 + col) * 32 + rg * 8];
#pragma unroll
        for (int ni = 0; ni < 2; ++ni)
            bfr[ni] = *(const bf16x8*)&Bs[(wave * 32 + ni * 16 + col) * 32 + rg * 8];
#pragma unroll
        for (int mi = 0; mi < 4; ++mi)
#pragma unroll
            for (int ni = 0; ni < 2; ++ni)
                acc[mi][ni] = __builtin_amdgcn_mfma_f32_16x16x32_bf16(
                    af[mi], bfr[ni], acc[mi][ni], 0, 0, 0);
        __syncthreads();
    }

    // C layout (validated): n-col = lane&15, m-row = (lane>>4)*4 + r
    const int h = (bn + wave * 32) >> 6;   // uniform per wave
#pragma unroll
    for (int mi = 0; mi < 4; ++mi) {
#pragma unroll
        for (int r = 0; r < 4; ++r) {
            const int m = bm + mi * 16 + rg * 4 + r;
            float mgv = 0.f;
            if (OUT) {
                const int bb = m / S, ss = m - bb * S;
                mgv = mg[(bb * NH + h) * S + ss];
            }
#pragma unroll
            for (int ni = 0; ni < 2; ++ni) {
                const int n = bn + wave * 32 + ni * 16 + col;
                const float val = acc[mi][ni][r] + bias[n];
                if (!OUT) Y[(size_t)m * DIM + n] = f2bu(val);
                else      Out[(size_t)m * DIM + n] = bf16r(val * mgv);
            }
        }
    }
}

// ---------------------------------------------------------------------------
// MFMA marginal kernel v4 — mask-compacted.
// Grid = NBH*2 (q-halves). vh/qh rows gathered via compacted index lists
// (masks are per-b). a kept uncompacted; masked a / pad v rows killed by a
// -200 exp2 offset (exact 0 in f32, fused into the existing fma).
// Wave w handles compact q-slots qs = qh0+w, +4, ... Reductions unchanged.
// ---------------------------------------------------------------------------
__global__ __launch_bounds__(256, 2) void attn_marginals_mfma(
    const unsigned short* __restrict__ vp, const unsigned short* __restrict__ qp,
    const unsigned short* __restrict__ ap,
    const int* __restrict__ amask,
    const int* __restrict__ vidx_g, const int* __restrict__ qidx_g,
    const int* __restrict__ cnts_g,
    float* __restrict__ pv_part, float* __restrict__ pa_part, float* __restrict__ pq_raw)
{
    const int bh = blockIdx.x >> 1, half = blockIdx.x & 1;
    const int b = bh / NH, h = bh % NH;
    const int tid = threadIdx.x, lane = tid & 63, wave = tid >> 6;
    const int col = lane & 15, rg = lane >> 4;

    __shared__ unsigned short vhs[112 * 72];   // bf16, compacted v rows
    __shared__ unsigned short qhs[NQ * 72];    // bf16, compacted q rows
    __shared__ unsigned short ahs[NA * 72];    // bf16, full a rows
    __shared__ int   vidx_sh[112];
    __shared__ float amoff[NA];
    __shared__ float pv_sh[112], pa_sh[NA];

    const int vcnt = cnts_g[b * 2 + 0];
    const int qcnt = cnts_g[b * 2 + 1];

    if (tid < 112) { vidx_sh[tid] = (tid < vcnt) ? vidx_g[b * NV + tid] : 0; pv_sh[tid] = 0.f; }
    if (tid < NA)  { amoff[tid] = amask[b * NA + tid] ? -200.f : 0.f; pa_sh[tid] = 0.f; }
    __syncthreads();

    // gather compacted v rows
    for (int i = tid >> 3; i < vcnt; i += 32) {
        const int c = tid & 7;
        *(u16x8*)&vhs[i * 72 + c * 8] =
            *(const u16x8*)&vp[(size_t)(b * NV + vidx_sh[i]) * DIM + h * 64 + c * 8];
    }
    // zero the pad rows of the last v-tile (garbage could be NaN patterns)
    {
        const int pr = vcnt + (tid >> 3);
        if ((tid >> 3) < 16 && pr < 112) {
            const int c = tid & 7;
            u16x8 z = {};
            *(u16x8*)&vhs[pr * 72 + c * 8] = z;
        }
    }
    // gather compacted q rows
    for (int i = tid >> 3; i < qcnt; i += 32) {
        const int c = tid & 7;
        *(u16x8*)&qhs[i * 72 + c * 8] =
            *(const u16x8*)&qp[(size_t)(b * NQ + qidx_g[b * NQ + i]) * DIM + h * 64 + c * 8];
    }
    // full a rows: 32 rows x 8 threads = 256
    {
        const int s = tid >> 3, c = tid & 7;
        *(u16x8*)&ahs[s * 72 + c * 8] =
            *(const u16x8*)&ap[(size_t)(b * NA + s) * DIM + h * 64 + c * 8];
    }
    __syncthreads();

    const int nvt = (vcnt + 15) >> 4;                  // uniform
    const int qmid = (qcnt + 1) >> 1;
    const int qh0 = half ? qmid : 0;
    const int qh1 = half ? qcnt : qmid;

    float pvacc[7][4] = {};
    float za0 = 0.f, za1 = 0.f;
    const float sc2 = 0.125f * 1.44269504088896f;      // scale * log2(e)

    for (int qs = qh0 + wave; qs < qh1; qs += 4) {
        float zq = 0.f;
#pragma unroll
        for (int ah = 0; ah < 2; ++ah) {
            const int ai = (ah << 4) + col;
            const u16x8 qv0 = *(const u16x8*)&qhs[qs * 72 + rg * 8];
            const u16x8 qv1 = *(const u16x8*)&qhs[qs * 72 + 32 + rg * 8];
            const u16x8 av0 = *(const u16x8*)&ahs[ai * 72 + rg * 8];
            const u16x8 av1 = *(const u16x8*)&ahs[ai * 72 + 32 + rg * 8];
            bf16x8 bf0, bf1;
#pragma unroll
            for (int j = 0; j < 8; ++j) {
                bf0[j] = (short)f2bu(bu2f(qv0[j]) * bu2f(av0[j]));
                bf1[j] = (short)f2bu(bu2f(qv1[j]) * bu2f(av1[j]));
            }
            const float poff = amoff[ai];
            float ts = 0.f;
#pragma unroll
            for (int vt = 0; vt < 7; ++vt) {
                if (vt < nvt) {
                    const bf16x8 a0 = *(const bf16x8*)&vhs[(vt * 16 + col) * 72 + rg * 8];
                    const bf16x8 a1 = *(const bf16x8*)&vhs[(vt * 16 + col) * 72 + 32 + rg * 8];
                    f32x4 acc = {};
                    acc = __builtin_amdgcn_mfma_f32_16x16x32_bf16(a0, bf0, acc, 0, 0, 0);
                    acc = __builtin_amdgcn_mfma_f32_16x16x32_bf16(a1, bf1, acc, 0, 0, 0);
                    if ((vt + 1) * 16 <= vcnt) {
#pragma unroll
                        for (int r = 0; r < 4; ++r) {
                            const float e = exp2f(fmaf(acc[r], sc2, poff));
                            pvacc[vt][r] += e;
                            ts += e;
                        }
                    } else {
#pragma unroll
                        for (int r = 0; r < 4; ++r) {
                            const float off = (vt * 16 + rg * 4 + r < vcnt) ? poff : -200.f;
                            const float e = exp2f(fmaf(acc[r], sc2, off));
                            pvacc[vt][r] += e;
                            ts += e;
                        }
                    }
                }
            }
            if (ah) za1 += ts; else za0 += ts;
            zq += ts;
        }
        zq += __shfl_xor(zq, 1);  zq += __shfl_xor(zq, 2);  zq += __shfl_xor(zq, 4);
        zq += __shfl_xor(zq, 8);  zq += __shfl_xor(zq, 16); zq += __shfl_xor(zq, 32);
        if (lane == 0) pq_raw[bh * NQ + qs] = zq;   // unique writer per qs
    }

    // end-of-kernel reductions
#pragma unroll
    for (int vt = 0; vt < 7; ++vt) {
        if (vt < nvt) {
#pragma unroll
            for (int r = 0; r < 4; ++r) {
                float x = pvacc[vt][r];
                x += __shfl_xor(x, 1); x += __shfl_xor(x, 2);
                x += __shfl_xor(x, 4); x += __shfl_xor(x, 8);
                if (col == 0) atomicAdd(&pv_sh[vt * 16 + rg * 4 + r], x);
            }
        }
    }
    {
        float x = za0;
        x += __shfl_xor(x, 16); x += __shfl_xor(x, 32);
        if (rg == 0) atomicAdd(&pa_sh[col], x);
        float y = za1;
        y += __shfl_xor(y, 16); y += __shfl_xor(y, 32);
        if (rg == 0) atomicAdd(&pa_sh[16 + col], y);
    }
    __syncthreads();
    if (tid < 112) pv_part[(size_t)(bh * 2 + half) * 112 + tid] = pv_sh[tid];
    if (tid < NA)  pa_part[(size_t)(bh * 2 + half) * NA + tid] = pa_sh[tid];
}

// ---------------------------------------------------------------------------
// Normalize: Z = sum of compact pq_raw, combine halves, scatter back to
// full-index marginal arrays (zeros for masked entries).
// ---------------------------------------------------------------------------
__global__ __launch_bounds__(128) void normalize_marg(
    const float* __restrict__ pv_part, const float* __restrict__ pa_part,
    const float* __restrict__ pq_raw,
    const int* __restrict__ vidx_g, const int* __restrict__ qidx_g,
    const int* __restrict__ cnts_g,
    float* __restrict__ pv, float* __restrict__ pq, float* __restrict__ pa)
{
    const int bh = blockIdx.x;
    const int b = bh / NH;
    const int tid = threadIdx.x, lane = tid & 63;
    const int vcnt = cnts_g[b * 2 + 0];
    const int qcnt = cnts_g[b * 2 + 1];
    __shared__ float zsh;
    if (tid < 64) {
        float x = (lane < qcnt) ? pq_raw[bh * NQ + lane] : 0.f;
        x += __shfl_xor(x, 1); x += __shfl_xor(x, 2); x += __shfl_xor(x, 4);
        x += __shfl_xor(x, 8); x += __shfl_xor(x, 16); x += __shfl_xor(x, 32);
        if (lane == 0) zsh = x;
    }
    if (tid < NV) pv[bh * NV + tid] = 0.f;
    if (tid < NQ) pq[bh * NQ + tid] = 0.f;
    __syncthreads();
    const float invZ = 1.0f / zsh;
    if (tid < vcnt)
        pv[bh * NV + vidx_g[b * NV + tid]] =
            (pv_part[(size_t)(bh * 2) * 112 + tid]
           + pv_part[(size_t)(bh * 2 + 1) * 112 + tid]) * invZ;
    if (tid < qcnt)
        pq[bh * NQ + qidx_g[b * NQ + tid]] = pq_raw[bh * NQ + tid] * invZ;
    if (tid < NA)
        pa[bh * NA + tid] = (pa_part[(size_t)(bh * 2) * NA + tid]
                           + pa_part[(size_t)(bh * 2 + 1) * NA + tid]) * invZ;
}

// ---------------------------------------------------------------------------
extern "C" void kernel_launch(void* const* d_in, const int* in_sizes, int n_in,
                              void* d_out, int out_size, void* d_ws, size_t ws_size,
                              hipStream_t stream)
{
    const float* v     = (const float*)d_in[0];
    const float* q     = (const float*)d_in[1];
    const float* a     = (const float*)d_in[2];
    const int*   vmask = (const int*)d_in[3];
    const int*   qmask = (const int*)d_in[4];
    const int*   amask = (const int*)d_in[5];
    const float* Wv  = (const float*)d_in[6];
    const float* bv  = (const float*)d_in[7];
    const float* Wq  = (const float*)d_in[8];
    const float* bq  = (const float*)d_in[9];
    const float* Wa  = (const float*)d_in[10];
    const float* ba  = (const float*)d_in[11];
    const float* Wvo = (const float*)d_in[12];
    const float* bvo = (const float*)d_in[13];
    const float* Wqo = (const float*)d_in[14];
    const float* bqo = (const float*)d_in[15];
    const float* Wao = (const float*)d_in[16];
    const float* bao = (const float*)d_in[17];
    float* out = (float*)d_out;          // reference output dtype is FLOAT32

    unsigned short* wsu = (unsigned short*)d_ws;
    unsigned short* WtAll = wsu;                    // 6 * 589824
    unsigned short* vpb   = WtAll + 6 * WELEMS;     // 2457600
    unsigned short* qpb   = vpb + VP_ELEMS;         // 786432
    unsigned short* apb   = qpb + QP_ELEMS;         // 786432
    float* fbase   = (float*)(apb + AP_ELEMS);
    float* pv_part = fbase;                         // 384*2*112 = 86016
    float* pa_part = pv_part + NBH * 2 * 112;       // 384*2*32  = 24576
    float* pq_raw  = pa_part + NBH * 2 * NA;        // 384*32    = 12288
    float* pv      = pq_raw + NBH * NQ;             // 384*100   = 38400
    float* pq      = pv + NBH * NV;                 // 384*32    = 12288
    float* pa      = pq + NBH * NQ;                 // 384*32    = 12288
    int* vidx_g    = (int*)(pa + NBH * NA);         // 32*100
    int* qidx_g    = vidx_g + BB * NV;              // 32*32
    int* cnts_g    = qidx_g + BB * NQ;              // 64
    // ws total ~15.5 MB

    compact_masks<<<dim3(BB), dim3(128), 0, stream>>>(vmask, qmask, vidx_g, qidx_g, cnts_g);
    conv_wT<<<dim3(6 * 144), dim3(256), 0, stream>>>(Wv, Wq, Wa, Wvo, Wqo, Wao, WtAll);

    gemm_mfma<0><<<dim3(492), dim3(256), 0, stream>>>(
        v, q, a,
        WtAll + 0 * WELEMS, WtAll + 1 * WELEMS, WtAll + 2 * WELEMS,
        bv, bq, ba,
        vpb, qpb, apb,
        nullptr, nullptr, nullptr,
        nullptr, nullptr, nullptr);

    attn_marginals_mfma<<<dim3(NBH * 2), dim3(256), 0, stream>>>(
        vpb, qpb, apb, amask, vidx_g, qidx_g, cnts_g, pv_part, pa_part, pq_raw);

    normalize_marg<<<dim3(NBH), dim3(128), 0, stream>>>(
        pv_part, pa_part, pq_raw, vidx_g, qidx_g, cnts_g, pv, pq, pa);

    gemm_mfma<1><<<dim3(492), dim3(256), 0, stream>>>(
        vpb, qpb, apb,
        WtAll + 3 * WELEMS, WtAll + 4 * WELEMS, WtAll + 5 * WELEMS,
        bvo, bqo, bao,
        nullptr, nullptr, nullptr,
        out, out + S1, out + S2,
        pv, pq, pa);
}